// Round 1
// baseline (12792.803 us; speedup 1.0000x reference)
//
#include <hip/hip_runtime.h>
#include <cmath>

// ---------------------------------------------------------------------------
// Graves handwriting synthesis: 3-layer GRU + attention window + MDN head
// B=32 T=512 U=64 V=60 H=400 K=10 M=20 IN=3
//
// Round 11: batched staging loads (latency de-serialization).
//  - stage_ring16 split into issue-phase (13 global loads into named regs,
//    fully unrolled -> all in flight together) + store-phase (unpack + LDS).
//    Previously the rolled loop exposed ~13 LLC latencies per ring per step
//    (L1/L2 stage TWO rings -> ~25 exposed latencies ~ 8us/step on the
//    serial critical path). Now ~1 latency per ring.
//  - L2 wring staging batched the same way (4 loads in flight).
//  Sync structure, math, fragments identical to r10 (passed, absmax 0.031).
// ---------------------------------------------------------------------------

typedef __attribute__((ext_vector_type(8))) short bf16x8;
typedef __attribute__((ext_vector_type(4))) float f32x4;
typedef unsigned short ushort_t;

namespace {
constexpr int B_ = 32, T_ = 512, U_ = 64, V_ = 60, H_ = 400, K_ = 10, M_ = 20;
constexpr int N_ = B_ * T_;          // 16384
constexpr int SEG = 416, FEAT_LD = 1248;
constexpr int NBLK = 150;
constexpr int SBL = 872;             // B-row stride in LDS (u16), 16B-aligned

// workspace layout (float indices)
constexpr size_t OFF_R0    = 0;                       // 4*32*400 u32 per ring
constexpr size_t OFF_R1    = 51200;
constexpr size_t OFF_R2    = 102400;
constexpr size_t OFF_WRING = 153600;                  // 4*32*60 f32
constexpr size_t OFF_BAR   = 161280;                  // 1088 uints
constexpr size_t ZERO_TOT  = OFF_BAR + 1088;
constexpr size_t OFF_FEATH = ZERO_TOT;                // N*1248 bf16
constexpr size_t OFF_FEATL = OFF_FEATH + (size_t)N_ * FEAT_LD / 2;
constexpr size_t OFF_WHH   = OFF_FEATL + (size_t)N_ * FEAT_LD / 2;  // 128*1248 bf16
constexpr size_t OFF_WHL   = OFF_WHH + (size_t)128 * FEAT_LD / 2;
constexpr size_t OFF_P     = OFF_WHL + (size_t)128 * FEAT_LD / 2;   // N*128 f32

// bar layout (uints): flags for group g (= L*2 + half) at [128 + 64*g + s],
// s = slice 0..24. 64-uint stride keeps each group on its own cache lines.
constexpr int BAR_FLAGS = 128;

// d_out layout (floats), reference return order
constexpr int DO_MEANS = 0;
constexpr int DO_STD   = B_ * T_ * M_ * 2;
constexpr int DO_LOGW  = DO_STD + B_ * T_ * M_;
constexpr int DO_CORR  = DO_LOGW + B_ * T_ * M_;
constexpr int DO_LAST  = DO_CORR + B_ * T_ * M_;
constexpr int DO_PHI   = DO_LAST + B_ * T_;
} // namespace

// ---------------------------------------------------------------------------
__device__ __forceinline__ float load_agent(const float* p) {
  return __hip_atomic_load(p, __ATOMIC_RELAXED, __HIP_MEMORY_SCOPE_AGENT);
}
__device__ __forceinline__ void store_agent(float* p, float v) {
  __hip_atomic_store(p, v, __ATOMIC_RELAXED, __HIP_MEMORY_SCOPE_AGENT);
}
__device__ __forceinline__ void store_agent_u32(unsigned* p, unsigned v) {
  __hip_atomic_store(p, v, __ATOMIC_RELAXED, __HIP_MEMORY_SCOPE_AGENT);
}
__device__ __forceinline__ unsigned load_agent_u32(const unsigned* p) {
  return __hip_atomic_load(p, __ATOMIC_RELAXED, __HIP_MEMORY_SCOPE_AGENT);
}
__device__ __forceinline__ unsigned long long load_agent_u64(const unsigned long long* p) {
  return __hip_atomic_load(p, __ATOMIC_RELAXED, __HIP_MEMORY_SCOPE_AGENT);
}
__device__ __forceinline__ ushort_t f2bf(float f) {
  union { float f; unsigned u; } x{f};
  unsigned r = x.u + 0x7FFFu + ((x.u >> 16) & 1u);
  return (ushort_t)(r >> 16);
}
__device__ __forceinline__ void split2(float f, ushort_t& h, ushort_t& l) {
  h = f2bf(f);
  union { unsigned u; float f; } c;
  c.u = ((unsigned)h) << 16;
  l = f2bf(f - c.f);
}
__device__ __forceinline__ float bfpair(ushort_t h, ushort_t l) {
  union { unsigned u; float f; } a, b;
  a.u = ((unsigned)h) << 16; b.u = ((unsigned)l) << 16;
  return a.f + b.f;
}
__device__ __forceinline__ float sigmoidf_(float x) {
  return 1.f / (1.f + __expf(-x));
}

// wave-parallel poll: lane i watches flags[i] (i<nf) until >= target.
__device__ __forceinline__ void wave_poll(const unsigned* flags, int nf, int target) {
  if (target <= 0) return;
  const int lane = threadIdx.x & 63;
  const unsigned* p = flags + (lane < nf ? lane : 0);
  for (;;) {
    int v = (int)load_agent_u32(p);
    if (__all(lane >= nf || v >= target)) break;
    __builtin_amdgcn_s_sleep(1);
  }
}

// ---------------------------------------------------------------------------
// Batched staging of one packed-ring 16x400 region into LDS split arrays.
// Issue phase: 12 (+1 tail) global loads fully unrolled -> all in flight.
// Store phase: unpack + ds_write, consuming loads in issue order so the
// compiler emits decreasing vmcnt waits (one exposed latency total).
// 6400 u32 elems = 3200 u64; threads 0..127 carry a 13th element.
__device__ __forceinline__ void stage_ring16(const unsigned* __restrict__ src,
                                             ushort_t* __restrict__ BhB,
                                             ushort_t* __restrict__ BlB, int koff) {
  const int tid = threadIdx.x;
  unsigned long long v[13];
#pragma unroll
  for (int i = 0; i < 12; ++i)
    v[i] = load_agent_u64((const unsigned long long*)(src + (tid + i * 256) * 2));
  const bool tail = tid < 128;
  if (tail)
    v[12] = load_agent_u64((const unsigned long long*)(src + (3072 + tid) * 2));
#pragma unroll
  for (int i = 0; i < 12; ++i) {
    int e = (tid + i * 256) * 2;
    int b = e / 400, k = e - b * 400;
    unsigned p0 = (unsigned)v[i], p1 = (unsigned)(v[i] >> 32);
    *(unsigned*)(BhB + b * SBL + koff + k) = (p0 >> 16) | (p1 & 0xFFFF0000u);
    *(unsigned*)(BlB + b * SBL + koff + k) = (p0 & 0xFFFFu) | (p1 << 16);
  }
  if (tail) {
    int e = (3072 + tid) * 2;
    int b = e / 400, k = e - b * 400;
    unsigned p0 = (unsigned)v[12], p1 = (unsigned)(v[12] >> 32);
    *(unsigned*)(BhB + b * SBL + koff + k) = (p0 >> 16) | (p1 & 0xFFFF0000u);
    *(unsigned*)(BlB + b * SBL + koff + k) = (p0 & 0xFFFFu) | (p1 << 16);
  }
}

// ---------------------------------------------------------------------------
__global__ __launch_bounds__(256)
void zero_ws(float* __restrict__ p) {
  size_t i = (size_t)blockIdx.x * 256 + threadIdx.x;
  if (i < ZERO_TOT) p[i] = 0.f;
}

__global__ void zero_feat_pads(ushort_t* __restrict__ fh, ushort_t* __restrict__ fl) {
  int idx = blockIdx.x * 256 + threadIdx.x;
  if (idx >= N_ * 48) return;
  int n = idx / 48, r = idx % 48;
  size_t o = (size_t)n * FEAT_LD + (r / 16) * SEG + 400 + (r % 16);
  fh[o] = 0; fl[o] = 0;
}

__global__ void split_wh_kernel(const float* __restrict__ Wh,
                                ushort_t* __restrict__ hi, ushort_t* __restrict__ lo) {
  int idx = blockIdx.x * 256 + threadIdx.x;
  if (idx >= 128 * FEAT_LD) return;
  int m = idx / FEAT_LD, k = idx % FEAT_LD;
  int seg = k / SEG, off = k % SEG;
  float v = (m < 121 && off < 400) ? Wh[(size_t)m * 1200 + seg * 400 + off] : 0.f;
  ushort_t h, l; split2(v, h, l);
  hi[idx] = h; lo[idx] = l;
}

__global__ __launch_bounds__(256)
void gemm_split_kernel(const ushort_t* __restrict__ Ahi, const ushort_t* __restrict__ Alo,
                       const ushort_t* __restrict__ Bhi, const ushort_t* __restrict__ Blo,
                       const float* __restrict__ bias, float* __restrict__ C,
                       int mtiles, int ntiles, int ktiles, int strideA, int strideB,
                       int Mvalid, int ldc) {
  int wave = blockIdx.x * 4 + (threadIdx.x >> 6);
  if (wave >= mtiles * ntiles) return;
  int mt = wave / ntiles, nt = wave % ntiles;
  int lane = threadIdx.x & 63, l15 = lane & 15, quad = lane >> 4;
  size_t aoff = (size_t)(mt * 16 + l15) * strideA + quad * 8;
  size_t boff = (size_t)(nt * 16 + l15) * strideB + quad * 8;
  f32x4 acc = {0.f, 0.f, 0.f, 0.f};
  for (int kt = 0; kt < ktiles; ++kt) {
    bf16x8 ah = *(const bf16x8*)(Ahi + aoff + kt * 32);
    bf16x8 al = *(const bf16x8*)(Alo + aoff + kt * 32);
    bf16x8 bh = *(const bf16x8*)(Bhi + boff + kt * 32);
    bf16x8 bl = *(const bf16x8*)(Blo + boff + kt * 32);
    acc = __builtin_amdgcn_mfma_f32_16x16x32_bf16(ah, bh, acc, 0, 0, 0);
    acc = __builtin_amdgcn_mfma_f32_16x16x32_bf16(ah, bl, acc, 0, 0, 0);
    acc = __builtin_amdgcn_mfma_f32_16x16x32_bf16(al, bh, acc, 0, 0, 0);
  }
  int n = nt * 16 + l15;
#pragma unroll
  for (int r = 0; r < 4; ++r) {
    int m = mt * 16 + quad * 4 + r;
    if (m < Mvalid) C[(size_t)n * ldc + m] = acc[r] + bias[m];
  }
}

// ---------------------------------------------------------------------------
// fused pipelined scan body (templated per layer)
template <int L>
__device__ __forceinline__ void scan_body(
    int slice, int bhalf,
    const float* __restrict__ x, const int* __restrict__ c,
    const float* __restrict__ Wih, const float* __restrict__ Whh,
    const float* __restrict__ bih, const float* __restrict__ bhh,
    const float* __restrict__ Ww, const float* __restrict__ bw,
    unsigned* __restrict__ ringS, const unsigned* __restrict__ ringP,
    const float* __restrict__ wring_c, float* __restrict__ wring_w,
    ushort_t* __restrict__ fh, ushort_t* __restrict__ fl,
    float* __restrict__ out_phi, unsigned* __restrict__ bar,
    ushort_t* Bh, ushort_t* Bl, float (*su)[65], float (*sp)[33],
    float (*skap)[10], unsigned char (*sc)[64]) {
  constexpr int KT = (L == 0) ? 15 : 27;
  constexpr int CONST_K = (L == 0) ? 463 : 863;
  constexpr int XOFF = (L == 0) ? 460 : 860;
  constexpr int WOFF = (L == 0) ? 400 : 800;
  constexpr int IW = (L == 0) ? 63 : 463;
  const int tid = threadIdx.x;
  const int waveid = tid >> 6, lane = tid & 63;
  const int l15 = lane & 15, quad = lane >> 4;
  const int rt = waveid;                 // rowtile 0..3
  const int m = l15;
  const int uu = m & 3, gate = m >> 2;   // 0=r 1=z 2=hn 3=inn
  const int J = slice * 16 + rt * 4 + uu;
  const int B0 = bhalf * 16;             // first global sample of this block

  // flag plumbing: own / parent / child flag arrays
  unsigned* fOwn    = bar + BAR_FLAGS + 64 * (L * 2 + bhalf);
  unsigned* fParent = (L >= 1) ? bar + BAR_FLAGS + 64 * ((L - 1) * 2 + bhalf) : nullptr;
  unsigned* fChild  = (L <= 1) ? bar + BAR_FLAGS + 64 * ((L + 1) * 2 + bhalf) : nullptr;

  // ---- main A-fragments (split bf16), in registers for all 512 steps ----
  bf16x8 afh[KT], afl[KT];
#pragma unroll
  for (int kt = 0; kt < KT; ++kt) {
    union { bf16x8 v; ushort_t s[8]; } uh, ul;
#pragma unroll
    for (int j = 0; j < 8; ++j) {
      int k = kt * 32 + quad * 8 + j;
      float v = 0.f;
      if (k < 400) {
        if (gate == 0)      v = Whh[(size_t)J * 400 + k];
        else if (gate == 1) v = Whh[(size_t)(400 + J) * 400 + k];
        else if (gate == 2) v = Whh[(size_t)(800 + J) * 400 + k];
      } else if (k < CONST_K) {
        int col;
        if (L == 0) col = (k < 460) ? 3 + (k - 400) : (k - 460);
        else        col = (k < 800) ? 3 + (k - 400)
                        : (k < 860) ? 403 + (k - 800) : (k - 860);
        if (gate == 0)      v = Wih[(size_t)J * IW + col];
        else if (gate == 1) v = Wih[(size_t)(400 + J) * IW + col];
        else if (gate == 3) v = Wih[(size_t)(800 + J) * IW + col];
      } else if (k == CONST_K) {
        if (gate == 0)      v = bih[J] + bhh[J];
        else if (gate == 1) v = bih[400 + J] + bhh[400 + J];
        else if (gate == 2) v = bhh[800 + J];
        else                v = bih[800 + J];
      }
      ushort_t h, l; split2(v, h, l);
      uh.s[j] = h; ul.s[j] = l;
    }
    afh[kt] = uh.v; afl[kt] = ul.v;
  }

  // ---- attention p-fragments (Ww rows, split), L0/L1: waves 0/1 own 16 rows
  bf16x8 apfh[14], apfl[14];
  if constexpr (L <= 1) {
    const int prow = (waveid < 2) ? (waveid * 16 + l15) : 32;
#pragma unroll
    for (int pk = 0; pk < 14; ++pk) {
      int kt = (pk < 13) ? ((L == 0) ? pk : 12 + pk) : ((L == 0) ? 14 : 26);
      union { bf16x8 v; ushort_t s[8]; } uh, ul;
#pragma unroll
      for (int j = 0; j < 8; ++j) {
        int k = kt * 32 + quad * 8 + j;
        int col = k - ((L == 0) ? 0 : 400);
        float v = 0.f;
        if (prow < 30) {
          if (col >= 0 && col < 400) v = Ww[prow * 400 + col];
          else if (k == CONST_K)     v = bw[prow];
        }
        ushort_t h, l; split2(v, h, l);
        uh.s[j] = h; ul.s[j] = l;
      }
      apfh[pk] = uh.v; apfl[pk] = ul.v;
    }
  }

  // ---- one-time LDS init ----
  for (int i = tid; i < 16 * SBL; i += 256) { Bh[i] = 0; Bl[i] = 0; }
  for (int i = tid; i < 160; i += 256) skap[i / 10][i % 10] = 0.f;
  if constexpr (L <= 1) {
    for (int i = tid; i < 16 * 64; i += 256)
      sc[i >> 6][i & 63] = (unsigned char)c[(B0 + (i >> 6)) * U_ + (i & 63)];
  }
  __syncthreads();
  if (tid < 16) Bh[tid * SBL + CONST_K] = 0x3F80;  // bf16(1.0); lo stays 0
  __syncthreads();

  // ---- time loop: dataflow sync via wave-parallel flag polls ----
  for (int t = 0; t < T_; ++t) {
    if (waveid == 0)      wave_poll(fOwn, 25, t);             // peers done t-1
    else if (waveid == 1) { if (L >= 1) wave_poll(fParent, 25, t + 1); }
    else if (waveid == 2) { if (L <= 1) wave_poll(fChild, 25, t - 3); }
    __syncthreads();

    // -- staging: own h(t-1); L>=1 also h_prev(t); L2 also w(t); x(t) --
    stage_ring16(ringS + (size_t)((t + 3) & 3) * 12800 + B0 * 400, Bh, Bl, 0);
    if constexpr (L >= 1)
      stage_ring16(ringP + (size_t)(t & 3) * 12800 + B0 * 400, Bh, Bl, 400);
    if constexpr (L == 2) {
      const float* srcw = wring_c + (size_t)(t & 3) * 1920 + B0 * 60;
      float wv[4];
#pragma unroll
      for (int i = 0; i < 3; ++i) wv[i] = load_agent(srcw + tid + i * 256);
      const bool wtail = tid < 192;
      if (wtail) wv[3] = load_agent(srcw + 768 + tid);
#pragma unroll
      for (int i = 0; i < 3; ++i) {
        int idx = tid + i * 256;
        int b = idx / 60, v = idx - b * 60;
        ushort_t h, l; split2(wv[i], h, l);
        Bh[b * SBL + WOFF + v] = h; Bl[b * SBL + WOFF + v] = l;
      }
      if (wtail) {
        int idx = 768 + tid;
        int b = idx / 60, v = idx - b * 60;
        ushort_t h, l; split2(wv[3], h, l);
        Bh[b * SBL + WOFF + v] = h; Bl[b * SBL + WOFF + v] = l;
      }
    }
    if (tid < 48) {
      int b = tid / 3, xc = tid - b * 3;
      ushort_t h, l;
      split2(x[((size_t)(B0 + b) * T_ + t) * 3 + xc], h, l);
      Bh[b * SBL + XOFF + xc] = h; Bl[b * SBL + XOFF + xc] = l;
    }
    __syncthreads();

    // -- attention (L0 computes w(t-1) for own input; L1 computes w(t)) --
    if constexpr (L <= 1) {
      const bool dow = (L == 1) || (t > 0);
      if (dow) {
        if (waveid < 2) {  // p-MFMA: rows waveid*16..+15 of 30, cols 16
          f32x4 acc = {0.f, 0.f, 0.f, 0.f};
          const int brow = l15 * SBL + quad * 8;
#pragma unroll
          for (int pk = 0; pk < 14; ++pk) {
            int kt = (pk < 13) ? ((L == 0) ? pk : 12 + pk) : ((L == 0) ? 14 : 26);
            bf16x8 bh8 = *(const bf16x8*)(Bh + brow + kt * 32);
            bf16x8 bl8 = *(const bf16x8*)(Bl + brow + kt * 32);
            acc = __builtin_amdgcn_mfma_f32_16x16x32_bf16(apfh[pk], bh8, acc, 0, 0, 0);
            acc = __builtin_amdgcn_mfma_f32_16x16x32_bf16(apfh[pk], bl8, acc, 0, 0, 0);
            acc = __builtin_amdgcn_mfma_f32_16x16x32_bf16(apfl[pk], bh8, acc, 0, 0, 0);
          }
#pragma unroll
          for (int r = 0; r < 4; ++r)
            sp[l15][waveid * 16 + quad * 4 + r] = acc[r];
        }
        __syncthreads();
        for (int idx = tid; idx < 480; idx += 256) {     // exp(p)
          int b = idx / 30, mm = idx - b * 30;
          sp[b][mm] = __expf(sp[b][mm]);
        }
        __syncthreads();
        for (int idx = tid; idx < 160; idx += 256) {     // kappa += dk
          int b = idx / 10, k2 = idx - b * 10;
          skap[b][k2] += sp[b][20 + k2];
        }
        __syncthreads();
        for (int idx = tid; idx < 1040; idx += 256) {    // phi
          int b = idx / 65, u = idx - b * 65;
          float s = 0.f;
#pragma unroll
          for (int k2 = 0; k2 < 10; ++k2) {
            float d = skap[b][k2] - (float)u;
            s = fmaf(sp[b][k2], __expf(-sp[b][10 + k2] * d * d), s);
          }
          su[b][u] = s;
        }
        __syncthreads();
        for (int idx = tid; idx < 960; idx += 256) {     // w gather
          int b = idx / 60, v = idx - b * 60;
          float s = 0.f;
#pragma unroll 8
          for (int u = 0; u < U_; ++u)
            s += (sc[b][u] == v) ? su[b][u] : 0.f;
          ushort_t h, l; split2(s, h, l);
          Bh[b * SBL + WOFF + v] = h; Bl[b * SBL + WOFF + v] = l;
          if (L == 1 && slice == 0)                      // publish w(t) for L2
            store_agent(wring_w + (size_t)(t & 3) * 1920 + B0 * 60 + idx, s);
        }
        if (L == 1 && t == T_ - 1 && slice == 0) {
          for (int idx = tid; idx < 1040; idx += 256)
            out_phi[(B0 + idx / 65) * 65 + (idx % 65)] = su[idx / 65][idx % 65];
        }
        __syncthreads();
      }
    }

    // -- main MFMA: rows = this wave's rowtile, cols = 16 samples --
    {
      f32x4 acc = {0.f, 0.f, 0.f, 0.f};
      const int brow = l15 * SBL + quad * 8;
#pragma unroll
      for (int kt = 0; kt < KT; ++kt) {
        bf16x8 bh8 = *(const bf16x8*)(Bh + brow + kt * 32);
        bf16x8 bl8 = *(const bf16x8*)(Bl + brow + kt * 32);
        acc = __builtin_amdgcn_mfma_f32_16x16x32_bf16(afh[kt], bh8, acc, 0, 0, 0);
        acc = __builtin_amdgcn_mfma_f32_16x16x32_bf16(afh[kt], bl8, acc, 0, 0, 0);
        acc = __builtin_amdgcn_mfma_f32_16x16x32_bf16(afl[kt], bh8, acc, 0, 0, 0);
      }
#pragma unroll
      for (int r = 0; r < 4; ++r)
        su[l15][rt * 16 + quad * 4 + r] = acc[r];   // su as sdots
    }
    __syncthreads();

    // -- combine: 256 threads = 16 samples x 16 units (unit fastest) --
    {
      int b = tid >> 4, u = tid & 15;
      int urt = u >> 2, u3 = u & 3;
      float rr = sigmoidf_(su[b][urt * 16 + 0 * 4 + u3]);
      float zz = sigmoidf_(su[b][urt * 16 + 1 * 4 + u3]);
      float hn = su[b][urt * 16 + 2 * 4 + u3];
      float inn = su[b][urt * 16 + 3 * 4 + u3];
      int Jc = slice * 16 + u;
      float hold = bfpair(Bh[b * SBL + Jc], Bl[b * SBL + Jc]);
      float hv = (1.f - zz) * tanhf(inn + rr * hn) + zz * hold;
      ushort_t hh, hl; split2(hv, hh, hl);
      store_agent_u32(ringS + (size_t)(t & 3) * 12800 + (B0 + b) * 400 + Jc,
                      ((unsigned)hh << 16) | (unsigned)hl);
      int n = (B0 + b) * T_ + t;
      size_t fo = (size_t)n * FEAT_LD + L * SEG + Jc;
      fh[fo] = hh; fl[fo] = hl;
    }

    // -- drain all stores, publish own flag (t+1) --
    __builtin_amdgcn_s_waitcnt(0);
    __syncthreads();
    if (tid == 0) store_agent_u32(fOwn + slice, (unsigned)(t + 1));
  }
}

__global__ __launch_bounds__(256, 1)
void fused_scan(const float* __restrict__ x, const int* __restrict__ c,
                const float* Wih0, const float* Whh0, const float* bih0, const float* bhh0,
                const float* Wih1, const float* Whh1, const float* bih1, const float* bhh1,
                const float* Wih2, const float* Whh2, const float* bih2, const float* bhh2,
                const float* __restrict__ Ww, const float* __restrict__ bw,
                unsigned* ring0, unsigned* ring1, unsigned* ring2, float* wring,
                ushort_t* __restrict__ fh, ushort_t* __restrict__ fl,
                float* __restrict__ out_phi, unsigned* __restrict__ bar) {
  __shared__ ushort_t Bh[16 * SBL];
  __shared__ ushort_t Bl[16 * SBL];
  __shared__ float su[16][65];     // sdots (64 rows) UNION sphi (65)
  __shared__ float sp[16][33];     // attention p (exp'ed); rows 30,31 unused
  __shared__ float skap[16][10];
  __shared__ unsigned char sc[16][64];

  const int bx = blockIdx.x;
  const int grpL = bx / 50, r = bx % 50;
  const int slice = r >> 1, bhalf = r & 1;

  if (grpL == 0)
    scan_body<0>(slice, bhalf, x, c, Wih0, Whh0, bih0, bhh0, Ww, bw,
                 ring0, nullptr, nullptr, nullptr, fh, fl, out_phi, bar,
                 Bh, Bl, su, sp, skap, sc);
  else if (grpL == 1)
    scan_body<1>(slice, bhalf, x, c, Wih1, Whh1, bih1, bhh1, Ww, bw,
                 ring1, ring0, nullptr, wring, fh, fl, out_phi, bar,
                 Bh, Bl, su, sp, skap, sc);
  else
    scan_body<2>(slice, bhalf, x, c, Wih2, Whh2, bih2, bhh2, Ww, bw,
                 ring2, ring1, wring, nullptr, fh, fl, out_phi, bar,
                 Bh, Bl, su, sp, skap, sc);
}

// ---------------------------------------------------------------------------
__global__ __launch_bounds__(256)
void post_kernel(const float* __restrict__ p, float* __restrict__ dout) {
  int n = blockIdx.x * 256 + threadIdx.x;
  if (n >= N_) return;
  const float* r = p + (size_t)n * 128;
  dout[DO_LAST + n] = r[0];
  float mx = -1e30f;
  for (int m = 0; m < M_; ++m) mx = fmaxf(mx, r[1 + m]);
  float s = 0.f;
  for (int m = 0; m < M_; ++m) s += __expf(r[1 + m] - mx);
  float lse = mx + logf(s);
  for (int m = 0; m < M_; ++m) dout[DO_LOGW + (size_t)n * M_ + m] = r[1 + m] - lse;
  for (int i = 0; i < 2 * M_; ++i) dout[DO_MEANS + (size_t)n * 2 * M_ + i] = r[21 + i];
  for (int m = 0; m < M_; ++m) dout[DO_STD + (size_t)n * M_ + m] = __expf(r[61 + m]);
  for (int m = 0; m < M_; ++m) dout[DO_CORR + (size_t)n * M_ + m] = tanhf(r[81 + m]);
}

// ---------------------------------------------------------------------------
extern "C" void kernel_launch(void* const* d_in, const int* in_sizes, int n_in,
                              void* d_out, int out_size, void* d_ws, size_t ws_size,
                              hipStream_t stream) {
  const float* x    = (const float*)d_in[0];
  const int*   c    = (const int*)d_in[1];
  const float* Wih0 = (const float*)d_in[2];
  const float* Whh0 = (const float*)d_in[3];
  const float* bih0 = (const float*)d_in[4];
  const float* bhh0 = (const float*)d_in[5];
  const float* Wih1 = (const float*)d_in[6];
  const float* Whh1 = (const float*)d_in[7];
  const float* bih1 = (const float*)d_in[8];
  const float* bhh1 = (const float*)d_in[9];
  const float* Wih2 = (const float*)d_in[10];
  const float* Whh2 = (const float*)d_in[11];
  const float* bih2 = (const float*)d_in[12];
  const float* bhh2 = (const float*)d_in[13];
  const float* Ww   = (const float*)d_in[14];
  const float* bw   = (const float*)d_in[15];
  const float* Wh   = (const float*)d_in[16];
  const float* bh   = (const float*)d_in[17];
  (void)in_sizes; (void)n_in; (void)out_size; (void)ws_size;

  float* ws = (float*)d_ws;
  unsigned* ring0 = (unsigned*)(ws + OFF_R0);
  unsigned* ring1 = (unsigned*)(ws + OFF_R1);
  unsigned* ring2 = (unsigned*)(ws + OFF_R2);
  float*    wring = ws + OFF_WRING;
  unsigned* bar   = (unsigned*)(ws + OFF_BAR);
  ushort_t* fh    = (ushort_t*)(ws + OFF_FEATH);
  ushort_t* fl    = (ushort_t*)(ws + OFF_FEATL);
  ushort_t* whh_  = (ushort_t*)(ws + OFF_WHH);
  ushort_t* whl_  = (ushort_t*)(ws + OFF_WHL);
  float*    pbuf  = ws + OFF_P;
  float*    dout  = (float*)d_out;

  const dim3 blk(256);

  zero_ws<<<dim3((int)((ZERO_TOT + 255) / 256)), blk, 0, stream>>>(ws);
  zero_feat_pads<<<dim3((N_ * 48) / 256), blk, 0, stream>>>(fh, fl);
  split_wh_kernel<<<dim3((128 * FEAT_LD) / 256), blk, 0, stream>>>(Wh, whh_, whl_);

  fused_scan<<<dim3(NBLK), blk, 0, stream>>>(
      x, c, Wih0, Whh0, bih0, bhh0, Wih1, Whh1, bih1, bhh1,
      Wih2, Whh2, bih2, bhh2, Ww, bw,
      ring0, ring1, ring2, wring, fh, fl, dout + DO_PHI, bar);

  gemm_split_kernel<<<dim3(8 * (N_ / 16) / 4), blk, 0, stream>>>(
      whh_, whl_, fh, fl, bh, pbuf, 8, N_ / 16, FEAT_LD / 32,
      FEAT_LD, FEAT_LD, 121, 128);
  post_kernel<<<dim3(N_ / 256), blk, 0, stream>>>(pbuf, dout);
}

// Round 7
// 7652.763 us; speedup vs baseline: 1.6717x; 1.6717x over previous
//
#include <hip/hip_runtime.h>
#include <cmath>

// ---------------------------------------------------------------------------
// Graves handwriting synthesis: 3-layer GRU + attention window + MDN head
// B=32 T=512 U=64 V=60 H=400 K=10 M=20 IN=3
//
// Round 12c (resubmit; r5/r6 GPU acquisition timed out). Latency-chain cuts
// inside the step (sync structure unchanged):
//  - 3-accumulator MFMA chains (main / attention / final GEMM): 81-deep
//    dependent acc chain -> 3 independent 27-deep chains (latency hidden).
//  - w-gather: 64-iter scan replaced by LDS atomicAdd scatter (4 atomics
//    per thread into sw[16][60]); exp+kappa phases merged (one barrier less).
//  - poll backoff: s_sleep escalates 1 -> 8 after 3 failed probes (cuts
//    LLC probe storm ~8x; tests the contention hypothesis).
//  Staging, fragments, flags identical to r11 (passed, absmax 0.031).
// ---------------------------------------------------------------------------

typedef __attribute__((ext_vector_type(8))) short bf16x8;
typedef __attribute__((ext_vector_type(4))) float f32x4;
typedef unsigned short ushort_t;

namespace {
constexpr int B_ = 32, T_ = 512, U_ = 64, V_ = 60, H_ = 400, K_ = 10, M_ = 20;
constexpr int N_ = B_ * T_;          // 16384
constexpr int SEG = 416, FEAT_LD = 1248;
constexpr int NBLK = 150;
constexpr int SBL = 872;             // B-row stride in LDS (u16), 16B-aligned

// workspace layout (float indices)
constexpr size_t OFF_R0    = 0;                       // 4*32*400 u32 per ring
constexpr size_t OFF_R1    = 51200;
constexpr size_t OFF_R2    = 102400;
constexpr size_t OFF_WRING = 153600;                  // 4*32*60 f32
constexpr size_t OFF_BAR   = 161280;                  // 1088 uints
constexpr size_t ZERO_TOT  = OFF_BAR + 1088;
constexpr size_t OFF_FEATH = ZERO_TOT;                // N*1248 bf16
constexpr size_t OFF_FEATL = OFF_FEATH + (size_t)N_ * FEAT_LD / 2;
constexpr size_t OFF_WHH   = OFF_FEATL + (size_t)N_ * FEAT_LD / 2;  // 128*1248 bf16
constexpr size_t OFF_WHL   = OFF_WHH + (size_t)128 * FEAT_LD / 2;
constexpr size_t OFF_P     = OFF_WHL + (size_t)128 * FEAT_LD / 2;   // N*128 f32

// bar layout (uints): flags for group g (= L*2 + half) at [128 + 64*g + s],
// s = slice 0..24. 64-uint stride keeps each group on its own cache lines.
constexpr int BAR_FLAGS = 128;

// d_out layout (floats), reference return order
constexpr int DO_MEANS = 0;
constexpr int DO_STD   = B_ * T_ * M_ * 2;
constexpr int DO_LOGW  = DO_STD + B_ * T_ * M_;
constexpr int DO_CORR  = DO_LOGW + B_ * T_ * M_;
constexpr int DO_LAST  = DO_CORR + B_ * T_ * M_;
constexpr int DO_PHI   = DO_LAST + B_ * T_;
} // namespace

// ---------------------------------------------------------------------------
__device__ __forceinline__ float load_agent(const float* p) {
  return __hip_atomic_load(p, __ATOMIC_RELAXED, __HIP_MEMORY_SCOPE_AGENT);
}
__device__ __forceinline__ void store_agent(float* p, float v) {
  __hip_atomic_store(p, v, __ATOMIC_RELAXED, __HIP_MEMORY_SCOPE_AGENT);
}
__device__ __forceinline__ void store_agent_u32(unsigned* p, unsigned v) {
  __hip_atomic_store(p, v, __ATOMIC_RELAXED, __HIP_MEMORY_SCOPE_AGENT);
}
__device__ __forceinline__ unsigned load_agent_u32(const unsigned* p) {
  return __hip_atomic_load(p, __ATOMIC_RELAXED, __HIP_MEMORY_SCOPE_AGENT);
}
__device__ __forceinline__ unsigned long long load_agent_u64(const unsigned long long* p) {
  return __hip_atomic_load(p, __ATOMIC_RELAXED, __HIP_MEMORY_SCOPE_AGENT);
}
__device__ __forceinline__ ushort_t f2bf(float f) {
  union { float f; unsigned u; } x{f};
  unsigned r = x.u + 0x7FFFu + ((x.u >> 16) & 1u);
  return (ushort_t)(r >> 16);
}
__device__ __forceinline__ void split2(float f, ushort_t& h, ushort_t& l) {
  h = f2bf(f);
  union { unsigned u; float f; } c;
  c.u = ((unsigned)h) << 16;
  l = f2bf(f - c.f);
}
__device__ __forceinline__ float bfpair(ushort_t h, ushort_t l) {
  union { unsigned u; float f; } a, b;
  a.u = ((unsigned)h) << 16; b.u = ((unsigned)l) << 16;
  return a.f + b.f;
}
__device__ __forceinline__ float sigmoidf_(float x) {
  return 1.f / (1.f + __expf(-x));
}

// wave-parallel poll: lane i watches flags[i] (i<nf) until >= target.
// Escalating backoff: short sleeps for the common just-about-ready case,
// longer sleeps when genuinely blocked (cuts LLC probe traffic ~8x).
// NOTE: s_sleep operand must be a compile-time constant -> two call sites.
__device__ __forceinline__ void wave_poll(const unsigned* flags, int nf, int target) {
  if (target <= 0) return;
  const int lane = threadIdx.x & 63;
  const unsigned* p = flags + (lane < nf ? lane : 0);
  int spins = 0;
  for (;;) {
    int v = (int)load_agent_u32(p);
    if (__all(lane >= nf || v >= target)) break;
    if (++spins > 3) __builtin_amdgcn_s_sleep(8);
    else             __builtin_amdgcn_s_sleep(1);
  }
}

// ---------------------------------------------------------------------------
// Batched staging of one packed-ring 16x400 region into LDS split arrays.
// Issue phase: 12 (+1 tail) global loads fully unrolled -> all in flight.
// Store phase: unpack + ds_write, consuming loads in issue order.
__device__ __forceinline__ void stage_ring16(const unsigned* __restrict__ src,
                                             ushort_t* __restrict__ BhB,
                                             ushort_t* __restrict__ BlB, int koff) {
  const int tid = threadIdx.x;
  unsigned long long v[13];
#pragma unroll
  for (int i = 0; i < 12; ++i)
    v[i] = load_agent_u64((const unsigned long long*)(src + (tid + i * 256) * 2));
  const bool tail = tid < 128;
  if (tail)
    v[12] = load_agent_u64((const unsigned long long*)(src + (3072 + tid) * 2));
#pragma unroll
  for (int i = 0; i < 12; ++i) {
    int e = (tid + i * 256) * 2;
    int b = e / 400, k = e - b * 400;
    unsigned p0 = (unsigned)v[i], p1 = (unsigned)(v[i] >> 32);
    *(unsigned*)(BhB + b * SBL + koff + k) = (p0 >> 16) | (p1 & 0xFFFF0000u);
    *(unsigned*)(BlB + b * SBL + koff + k) = (p0 & 0xFFFFu) | (p1 << 16);
  }
  if (tail) {
    int e = (3072 + tid) * 2;
    int b = e / 400, k = e - b * 400;
    unsigned p0 = (unsigned)v[12], p1 = (unsigned)(v[12] >> 32);
    *(unsigned*)(BhB + b * SBL + koff + k) = (p0 >> 16) | (p1 & 0xFFFF0000u);
    *(unsigned*)(BlB + b * SBL + koff + k) = (p0 & 0xFFFFu) | (p1 << 16);
  }
}

// ---------------------------------------------------------------------------
__global__ __launch_bounds__(256)
void zero_ws(float* __restrict__ p) {
  size_t i = (size_t)blockIdx.x * 256 + threadIdx.x;
  if (i < ZERO_TOT) p[i] = 0.f;
}

__global__ void zero_feat_pads(ushort_t* __restrict__ fh, ushort_t* __restrict__ fl) {
  int idx = blockIdx.x * 256 + threadIdx.x;
  if (idx >= N_ * 48) return;
  int n = idx / 48, r = idx % 48;
  size_t o = (size_t)n * FEAT_LD + (r / 16) * SEG + 400 + (r % 16);
  fh[o] = 0; fl[o] = 0;
}

__global__ void split_wh_kernel(const float* __restrict__ Wh,
                                ushort_t* __restrict__ hi, ushort_t* __restrict__ lo) {
  int idx = blockIdx.x * 256 + threadIdx.x;
  if (idx >= 128 * FEAT_LD) return;
  int m = idx / FEAT_LD, k = idx % FEAT_LD;
  int seg = k / SEG, off = k % SEG;
  float v = (m < 121 && off < 400) ? Wh[(size_t)m * 1200 + seg * 400 + off] : 0.f;
  ushort_t h, l; split2(v, h, l);
  hi[idx] = h; lo[idx] = l;
}

__global__ __launch_bounds__(256)
void gemm_split_kernel(const ushort_t* __restrict__ Ahi, const ushort_t* __restrict__ Alo,
                       const ushort_t* __restrict__ Bhi, const ushort_t* __restrict__ Blo,
                       const float* __restrict__ bias, float* __restrict__ C,
                       int mtiles, int ntiles, int ktiles, int strideA, int strideB,
                       int Mvalid, int ldc) {
  int wave = blockIdx.x * 4 + (threadIdx.x >> 6);
  if (wave >= mtiles * ntiles) return;
  int mt = wave / ntiles, nt = wave % ntiles;
  int lane = threadIdx.x & 63, l15 = lane & 15, quad = lane >> 4;
  size_t aoff = (size_t)(mt * 16 + l15) * strideA + quad * 8;
  size_t boff = (size_t)(nt * 16 + l15) * strideB + quad * 8;
  f32x4 a0 = {0.f, 0.f, 0.f, 0.f}, a1 = a0, a2 = a0;
  for (int kt = 0; kt < ktiles; ++kt) {
    bf16x8 ah = *(const bf16x8*)(Ahi + aoff + kt * 32);
    bf16x8 al = *(const bf16x8*)(Alo + aoff + kt * 32);
    bf16x8 bh = *(const bf16x8*)(Bhi + boff + kt * 32);
    bf16x8 bl = *(const bf16x8*)(Blo + boff + kt * 32);
    a0 = __builtin_amdgcn_mfma_f32_16x16x32_bf16(ah, bh, a0, 0, 0, 0);
    a1 = __builtin_amdgcn_mfma_f32_16x16x32_bf16(ah, bl, a1, 0, 0, 0);
    a2 = __builtin_amdgcn_mfma_f32_16x16x32_bf16(al, bh, a2, 0, 0, 0);
  }
  int n = nt * 16 + l15;
#pragma unroll
  for (int r = 0; r < 4; ++r) {
    int m = mt * 16 + quad * 4 + r;
    if (m < Mvalid) C[(size_t)n * ldc + m] = a0[r] + a1[r] + a2[r] + bias[m];
  }
}

// ---------------------------------------------------------------------------
// fused pipelined scan body (templated per layer)
template <int L>
__device__ __forceinline__ void scan_body(
    int slice, int bhalf,
    const float* __restrict__ x, const int* __restrict__ c,
    const float* __restrict__ Wih, const float* __restrict__ Whh,
    const float* __restrict__ bih, const float* __restrict__ bhh,
    const float* __restrict__ Ww, const float* __restrict__ bw,
    unsigned* __restrict__ ringS, const unsigned* __restrict__ ringP,
    const float* __restrict__ wring_c, float* __restrict__ wring_w,
    ushort_t* __restrict__ fh, ushort_t* __restrict__ fl,
    float* __restrict__ out_phi, unsigned* __restrict__ bar,
    ushort_t* Bh, ushort_t* Bl, float (*su)[65], float (*sp)[33],
    float (*skap)[10], unsigned char (*sc)[64], float (*sw)[60]) {
  constexpr int KT = (L == 0) ? 15 : 27;
  constexpr int CONST_K = (L == 0) ? 463 : 863;
  constexpr int XOFF = (L == 0) ? 460 : 860;
  constexpr int WOFF = (L == 0) ? 400 : 800;
  constexpr int IW = (L == 0) ? 63 : 463;
  const int tid = threadIdx.x;
  const int waveid = tid >> 6, lane = tid & 63;
  const int l15 = lane & 15, quad = lane >> 4;
  const int rt = waveid;                 // rowtile 0..3
  const int m = l15;
  const int uu = m & 3, gate = m >> 2;   // 0=r 1=z 2=hn 3=inn
  const int J = slice * 16 + rt * 4 + uu;
  const int B0 = bhalf * 16;             // first global sample of this block

  // flag plumbing: own / parent / child flag arrays
  unsigned* fOwn    = bar + BAR_FLAGS + 64 * (L * 2 + bhalf);
  unsigned* fParent = (L >= 1) ? bar + BAR_FLAGS + 64 * ((L - 1) * 2 + bhalf) : nullptr;
  unsigned* fChild  = (L <= 1) ? bar + BAR_FLAGS + 64 * ((L + 1) * 2 + bhalf) : nullptr;

  // ---- main A-fragments (split bf16), in registers for all 512 steps ----
  bf16x8 afh[KT], afl[KT];
#pragma unroll
  for (int kt = 0; kt < KT; ++kt) {
    union { bf16x8 v; ushort_t s[8]; } uh, ul;
#pragma unroll
    for (int j = 0; j < 8; ++j) {
      int k = kt * 32 + quad * 8 + j;
      float v = 0.f;
      if (k < 400) {
        if (gate == 0)      v = Whh[(size_t)J * 400 + k];
        else if (gate == 1) v = Whh[(size_t)(400 + J) * 400 + k];
        else if (gate == 2) v = Whh[(size_t)(800 + J) * 400 + k];
      } else if (k < CONST_K) {
        int col;
        if (L == 0) col = (k < 460) ? 3 + (k - 400) : (k - 460);
        else        col = (k < 800) ? 3 + (k - 400)
                        : (k < 860) ? 403 + (k - 800) : (k - 860);
        if (gate == 0)      v = Wih[(size_t)J * IW + col];
        else if (gate == 1) v = Wih[(size_t)(400 + J) * IW + col];
        else if (gate == 3) v = Wih[(size_t)(800 + J) * IW + col];
      } else if (k == CONST_K) {
        if (gate == 0)      v = bih[J] + bhh[J];
        else if (gate == 1) v = bih[400 + J] + bhh[400 + J];
        else if (gate == 2) v = bhh[800 + J];
        else                v = bih[800 + J];
      }
      ushort_t h, l; split2(v, h, l);
      uh.s[j] = h; ul.s[j] = l;
    }
    afh[kt] = uh.v; afl[kt] = ul.v;
  }

  // ---- attention p-fragments (Ww rows, split), L0/L1: waves 0/1 own 16 rows
  bf16x8 apfh[14], apfl[14];
  if constexpr (L <= 1) {
    const int prow = (waveid < 2) ? (waveid * 16 + l15) : 32;
#pragma unroll
    for (int pk = 0; pk < 14; ++pk) {
      int kt = (pk < 13) ? ((L == 0) ? pk : 12 + pk) : ((L == 0) ? 14 : 26);
      union { bf16x8 v; ushort_t s[8]; } uh, ul;
#pragma unroll
      for (int j = 0; j < 8; ++j) {
        int k = kt * 32 + quad * 8 + j;
        int col = k - ((L == 0) ? 0 : 400);
        float v = 0.f;
        if (prow < 30) {
          if (col >= 0 && col < 400) v = Ww[prow * 400 + col];
          else if (k == CONST_K)     v = bw[prow];
        }
        ushort_t h, l; split2(v, h, l);
        uh.s[j] = h; ul.s[j] = l;
      }
      apfh[pk] = uh.v; apfl[pk] = ul.v;
    }
  }

  // ---- one-time LDS init ----
  for (int i = tid; i < 16 * SBL; i += 256) { Bh[i] = 0; Bl[i] = 0; }
  for (int i = tid; i < 160; i += 256) skap[i / 10][i % 10] = 0.f;
  if constexpr (L <= 1) {
    for (int i = tid; i < 16 * 64; i += 256)
      sc[i >> 6][i & 63] = (unsigned char)c[(B0 + (i >> 6)) * U_ + (i & 63)];
  }
  __syncthreads();
  if (tid < 16) Bh[tid * SBL + CONST_K] = 0x3F80;  // bf16(1.0); lo stays 0
  __syncthreads();

  // ---- time loop: dataflow sync via wave-parallel flag polls ----
  for (int t = 0; t < T_; ++t) {
    if (waveid == 0)      wave_poll(fOwn, 25, t);             // peers done t-1
    else if (waveid == 1) { if (L >= 1) wave_poll(fParent, 25, t + 1); }
    else if (waveid == 2) { if (L <= 1) wave_poll(fChild, 25, t - 3); }
    __syncthreads();

    // -- staging: own h(t-1); L>=1 also h_prev(t); L2 also w(t); x(t) --
    stage_ring16(ringS + (size_t)((t + 3) & 3) * 12800 + B0 * 400, Bh, Bl, 0);
    if constexpr (L >= 1)
      stage_ring16(ringP + (size_t)(t & 3) * 12800 + B0 * 400, Bh, Bl, 400);
    if constexpr (L == 2) {
      const float* srcw = wring_c + (size_t)(t & 3) * 1920 + B0 * 60;
      float wv[4];
#pragma unroll
      for (int i = 0; i < 3; ++i) wv[i] = load_agent(srcw + tid + i * 256);
      const bool wtail = tid < 192;
      if (wtail) wv[3] = load_agent(srcw + 768 + tid);
#pragma unroll
      for (int i = 0; i < 3; ++i) {
        int idx = tid + i * 256;
        int b = idx / 60, v = idx - b * 60;
        ushort_t h, l; split2(wv[i], h, l);
        Bh[b * SBL + WOFF + v] = h; Bl[b * SBL + WOFF + v] = l;
      }
      if (wtail) {
        int idx = 768 + tid;
        int b = idx / 60, v = idx - b * 60;
        ushort_t h, l; split2(wv[3], h, l);
        Bh[b * SBL + WOFF + v] = h; Bl[b * SBL + WOFF + v] = l;
      }
    }
    if (tid < 48) {
      int b = tid / 3, xc = tid - b * 3;
      ushort_t h, l;
      split2(x[((size_t)(B0 + b) * T_ + t) * 3 + xc], h, l);
      Bh[b * SBL + XOFF + xc] = h; Bl[b * SBL + XOFF + xc] = l;
    }
    __syncthreads();

    // -- attention (L0 computes w(t-1) for own input; L1 computes w(t)) --
    if constexpr (L <= 1) {
      const bool dow = (L == 1) || (t > 0);
      if (dow) {
        if (waveid < 2) {  // p-MFMA: rows waveid*16..+15 of 30, cols 16
          f32x4 a0 = {0.f, 0.f, 0.f, 0.f}, a1 = a0, a2 = a0;
          const int brow = l15 * SBL + quad * 8;
#pragma unroll
          for (int pk = 0; pk < 14; ++pk) {
            int kt = (pk < 13) ? ((L == 0) ? pk : 12 + pk) : ((L == 0) ? 14 : 26);
            bf16x8 bh8 = *(const bf16x8*)(Bh + brow + kt * 32);
            bf16x8 bl8 = *(const bf16x8*)(Bl + brow + kt * 32);
            a0 = __builtin_amdgcn_mfma_f32_16x16x32_bf16(apfh[pk], bh8, a0, 0, 0, 0);
            a1 = __builtin_amdgcn_mfma_f32_16x16x32_bf16(apfh[pk], bl8, a1, 0, 0, 0);
            a2 = __builtin_amdgcn_mfma_f32_16x16x32_bf16(apfl[pk], bh8, a2, 0, 0, 0);
          }
#pragma unroll
          for (int r = 0; r < 4; ++r)
            sp[l15][waveid * 16 + quad * 4 + r] = a0[r] + a1[r] + a2[r];
        }
        __syncthreads();
        for (int idx = tid; idx < 480; idx += 256) {     // exp(p) + kappa
          int b = idx / 30, mm = idx - b * 30;
          float e = __expf(sp[b][mm]);
          sp[b][mm] = e;
          if (mm >= 20) skap[b][mm - 20] += e;           // kappa += dk
        }
        __syncthreads();
        for (int idx = tid; idx < 1040; idx += 256) {    // phi
          int b = idx / 65, u = idx - b * 65;
          float s = 0.f;
#pragma unroll
          for (int k2 = 0; k2 < 10; ++k2) {
            float d = skap[b][k2] - (float)u;
            s = fmaf(sp[b][k2], __expf(-sp[b][10 + k2] * d * d), s);
          }
          su[b][u] = s;
        }
        for (int idx = tid; idx < 960; idx += 256)       // zero w accum
          sw[idx / 60][idx % 60] = 0.f;
        __syncthreads();
        for (int idx = tid; idx < 1024; idx += 256) {    // scatter phi -> w
          int b = idx >> 6, u = idx & 63;
          atomicAdd(&sw[b][sc[b][u]], su[b][u]);
        }
        __syncthreads();
        for (int idx = tid; idx < 960; idx += 256) {     // write w into B
          int b = idx / 60, v = idx - b * 60;
          float s = sw[b][v];
          ushort_t h, l; split2(s, h, l);
          Bh[b * SBL + WOFF + v] = h; Bl[b * SBL + WOFF + v] = l;
          if (L == 1 && slice == 0)                      // publish w(t) for L2
            store_agent(wring_w + (size_t)(t & 3) * 1920 + B0 * 60 + idx, s);
        }
        if (L == 1 && t == T_ - 1 && slice == 0) {
          for (int idx = tid; idx < 1040; idx += 256)
            out_phi[(B0 + idx / 65) * 65 + (idx % 65)] = su[idx / 65][idx % 65];
        }
        __syncthreads();
      }
    }

    // -- main MFMA: rows = this wave's rowtile, cols = 16 samples --
    {
      f32x4 a0 = {0.f, 0.f, 0.f, 0.f}, a1 = a0, a2 = a0;
      const int brow = l15 * SBL + quad * 8;
#pragma unroll
      for (int kt = 0; kt < KT; ++kt) {
        bf16x8 bh8 = *(const bf16x8*)(Bh + brow + kt * 32);
        bf16x8 bl8 = *(const bf16x8*)(Bl + brow + kt * 32);
        a0 = __builtin_amdgcn_mfma_f32_16x16x32_bf16(afh[kt], bh8, a0, 0, 0, 0);
        a1 = __builtin_amdgcn_mfma_f32_16x16x32_bf16(afh[kt], bl8, a1, 0, 0, 0);
        a2 = __builtin_amdgcn_mfma_f32_16x16x32_bf16(afl[kt], bh8, a2, 0, 0, 0);
      }
#pragma unroll
      for (int r = 0; r < 4; ++r)
        su[l15][rt * 16 + quad * 4 + r] = a0[r] + a1[r] + a2[r];  // su as sdots
    }
    __syncthreads();

    // -- combine: 256 threads = 16 samples x 16 units (unit fastest) --
    {
      int b = tid >> 4, u = tid & 15;
      int urt = u >> 2, u3 = u & 3;
      float rr = sigmoidf_(su[b][urt * 16 + 0 * 4 + u3]);
      float zz = sigmoidf_(su[b][urt * 16 + 1 * 4 + u3]);
      float hn = su[b][urt * 16 + 2 * 4 + u3];
      float inn = su[b][urt * 16 + 3 * 4 + u3];
      int Jc = slice * 16 + u;
      float hold = bfpair(Bh[b * SBL + Jc], Bl[b * SBL + Jc]);
      float hv = (1.f - zz) * tanhf(inn + rr * hn) + zz * hold;
      ushort_t hh, hl; split2(hv, hh, hl);
      store_agent_u32(ringS + (size_t)(t & 3) * 12800 + (B0 + b) * 400 + Jc,
                      ((unsigned)hh << 16) | (unsigned)hl);
      int n = (B0 + b) * T_ + t;
      size_t fo = (size_t)n * FEAT_LD + L * SEG + Jc;
      fh[fo] = hh; fl[fo] = hl;
    }

    // -- drain all stores, publish own flag (t+1) --
    __builtin_amdgcn_s_waitcnt(0);
    __syncthreads();
    if (tid == 0) store_agent_u32(fOwn + slice, (unsigned)(t + 1));
  }
}

__global__ __launch_bounds__(256, 1)
void fused_scan(const float* __restrict__ x, const int* __restrict__ c,
                const float* Wih0, const float* Whh0, const float* bih0, const float* bhh0,
                const float* Wih1, const float* Whh1, const float* bih1, const float* bhh1,
                const float* Wih2, const float* Whh2, const float* bih2, const float* bhh2,
                const float* __restrict__ Ww, const float* __restrict__ bw,
                unsigned* ring0, unsigned* ring1, unsigned* ring2, float* wring,
                ushort_t* __restrict__ fh, ushort_t* __restrict__ fl,
                float* __restrict__ out_phi, unsigned* __restrict__ bar) {
  __shared__ ushort_t Bh[16 * SBL];
  __shared__ ushort_t Bl[16 * SBL];
  __shared__ float su[16][65];     // sdots (64 rows) UNION sphi (65)
  __shared__ float sp[16][33];     // attention p (exp'ed); rows 30,31 unused
  __shared__ float skap[16][10];
  __shared__ unsigned char sc[16][64];
  __shared__ float sw[16][60];     // w scatter accumulator

  const int bx = blockIdx.x;
  const int grpL = bx / 50, r = bx % 50;
  const int slice = r >> 1, bhalf = r & 1;

  if (grpL == 0)
    scan_body<0>(slice, bhalf, x, c, Wih0, Whh0, bih0, bhh0, Ww, bw,
                 ring0, nullptr, nullptr, nullptr, fh, fl, out_phi, bar,
                 Bh, Bl, su, sp, skap, sc, sw);
  else if (grpL == 1)
    scan_body<1>(slice, bhalf, x, c, Wih1, Whh1, bih1, bhh1, Ww, bw,
                 ring1, ring0, nullptr, wring, fh, fl, out_phi, bar,
                 Bh, Bl, su, sp, skap, sc, sw);
  else
    scan_body<2>(slice, bhalf, x, c, Wih2, Whh2, bih2, bhh2, Ww, bw,
                 ring2, ring1, wring, nullptr, fh, fl, out_phi, bar,
                 Bh, Bl, su, sp, skap, sc, sw);
}

// ---------------------------------------------------------------------------
__global__ __launch_bounds__(256)
void post_kernel(const float* __restrict__ p, float* __restrict__ dout) {
  int n = blockIdx.x * 256 + threadIdx.x;
  if (n >= N_) return;
  const float* r = p + (size_t)n * 128;
  dout[DO_LAST + n] = r[0];
  float mx = -1e30f;
  for (int m = 0; m < M_; ++m) mx = fmaxf(mx, r[1 + m]);
  float s = 0.f;
  for (int m = 0; m < M_; ++m) s += __expf(r[1 + m] - mx);
  float lse = mx + logf(s);
  for (int m = 0; m < M_; ++m) dout[DO_LOGW + (size_t)n * M_ + m] = r[1 + m] - lse;
  for (int i = 0; i < 2 * M_; ++i) dout[DO_MEANS + (size_t)n * 2 * M_ + i] = r[21 + i];
  for (int m = 0; m < M_; ++m) dout[DO_STD + (size_t)n * M_ + m] = __expf(r[61 + m]);
  for (int m = 0; m < M_; ++m) dout[DO_CORR + (size_t)n * M_ + m] = tanhf(r[81 + m]);
}

// ---------------------------------------------------------------------------
extern "C" void kernel_launch(void* const* d_in, const int* in_sizes, int n_in,
                              void* d_out, int out_size, void* d_ws, size_t ws_size,
                              hipStream_t stream) {
  const float* x    = (const float*)d_in[0];
  const int*   c    = (const int*)d_in[1];
  const float* Wih0 = (const float*)d_in[2];
  const float* Whh0 = (const float*)d_in[3];
  const float* bih0 = (const float*)d_in[4];
  const float* bhh0 = (const float*)d_in[5];
  const float* Wih1 = (const float*)d_in[6];
  const float* Whh1 = (const float*)d_in[7];
  const float* bih1 = (const float*)d_in[8];
  const float* bhh1 = (const float*)d_in[9];
  const float* Wih2 = (const float*)d_in[10];
  const float* Whh2 = (const float*)d_in[11];
  const float* bih2 = (const float*)d_in[12];
  const float* bhh2 = (const float*)d_in[13];
  const float* Ww   = (const float*)d_in[14];
  const float* bw   = (const float*)d_in[15];
  const float* Wh   = (const float*)d_in[16];
  const float* bh   = (const float*)d_in[17];
  (void)in_sizes; (void)n_in; (void)out_size; (void)ws_size;

  float* ws = (float*)d_ws;
  unsigned* ring0 = (unsigned*)(ws + OFF_R0);
  unsigned* ring1 = (unsigned*)(ws + OFF_R1);
  unsigned* ring2 = (unsigned*)(ws + OFF_R2);
  float*    wring = ws + OFF_WRING;
  unsigned* bar   = (unsigned*)(ws + OFF_BAR);
  ushort_t* fh    = (ushort_t*)(ws + OFF_FEATH);
  ushort_t* fl    = (ushort_t*)(ws + OFF_FEATL);
  ushort_t* whh_  = (ushort_t*)(ws + OFF_WHH);
  ushort_t* whl_  = (ushort_t*)(ws + OFF_WHL);
  float*    pbuf  = ws + OFF_P;
  float*    dout  = (float*)d_out;

  const dim3 blk(256);

  zero_ws<<<dim3((int)((ZERO_TOT + 255) / 256)), blk, 0, stream>>>(ws);
  zero_feat_pads<<<dim3((N_ * 48) / 256), blk, 0, stream>>>(fh, fl);
  split_wh_kernel<<<dim3((128 * FEAT_LD) / 256), blk, 0, stream>>>(Wh, whh_, whl_);

  fused_scan<<<dim3(NBLK), blk, 0, stream>>>(
      x, c, Wih0, Whh0, bih0, bhh0, Wih1, Whh1, bih1, bhh1,
      Wih2, Whh2, bih2, bhh2, Ww, bw,
      ring0, ring1, ring2, wring, fh, fl, dout + DO_PHI, bar);

  gemm_split_kernel<<<dim3(8 * (N_ / 16) / 4), blk, 0, stream>>>(
      whh_, whl_, fh, fl, bh, pbuf, 8, N_ / 16, FEAT_LD / 32,
      FEAT_LD, FEAT_LD, 121, 128);
  post_kernel<<<dim3(N_ / 256), blk, 0, stream>>>(pbuf, dout);
}

// Round 8
// 7409.496 us; speedup vs baseline: 1.7265x; 1.0328x over previous
//
#include <hip/hip_runtime.h>
#include <cmath>

// ---------------------------------------------------------------------------
// Graves handwriting synthesis: 3-layer GRU + attention window + MDN head
// B=32 T=512 U=64 V=60 H=400 K=10 M=20 IN=3
//
// Round 13: serial-structure cuts in the step (flag protocol unchanged).
//  - ONE staging issue phase: own ring (13) + parent ring (13) + wring (4)
//    + x loads all in flight together -> 1 exposed LLC latency (was 2-3).
//  - Wave-local attention: each wave owns 4 samples; exp/kappa/phi/scatter/
//    w-write are wave-internal -> 2 barriers in attention instead of 5.
//  - Feature (fh/fl) stores AFTER flag publish: the pre-flag drain now only
//    covers ring/wring stores; fh/fl ordering vs gemm = kernel boundary.
//  r12c (7653us, absmax 0.031): 3-acc MFMA chains, LDS-atomic w-scatter,
//  s_sleep backoff -- all kept.
// ---------------------------------------------------------------------------

typedef __attribute__((ext_vector_type(8))) short bf16x8;
typedef __attribute__((ext_vector_type(4))) float f32x4;
typedef unsigned short ushort_t;

namespace {
constexpr int B_ = 32, T_ = 512, U_ = 64, V_ = 60, H_ = 400, K_ = 10, M_ = 20;
constexpr int N_ = B_ * T_;          // 16384
constexpr int SEG = 416, FEAT_LD = 1248;
constexpr int NBLK = 150;
constexpr int SBL = 872;             // B-row stride in LDS (u16), 16B-aligned

// workspace layout (float indices)
constexpr size_t OFF_R0    = 0;                       // 4*32*400 u32 per ring
constexpr size_t OFF_R1    = 51200;
constexpr size_t OFF_R2    = 102400;
constexpr size_t OFF_WRING = 153600;                  // 4*32*60 f32
constexpr size_t OFF_BAR   = 161280;                  // 1088 uints
constexpr size_t ZERO_TOT  = OFF_BAR + 1088;
constexpr size_t OFF_FEATH = ZERO_TOT;                // N*1248 bf16
constexpr size_t OFF_FEATL = OFF_FEATH + (size_t)N_ * FEAT_LD / 2;
constexpr size_t OFF_WHH   = OFF_FEATL + (size_t)N_ * FEAT_LD / 2;  // 128*1248 bf16
constexpr size_t OFF_WHL   = OFF_WHH + (size_t)128 * FEAT_LD / 2;
constexpr size_t OFF_P     = OFF_WHL + (size_t)128 * FEAT_LD / 2;   // N*128 f32

// bar layout (uints): flags for group g (= L*2 + half) at [128 + 64*g + s],
// s = slice 0..24. 64-uint stride keeps each group on its own cache lines.
constexpr int BAR_FLAGS = 128;

// d_out layout (floats), reference return order
constexpr int DO_MEANS = 0;
constexpr int DO_STD   = B_ * T_ * M_ * 2;
constexpr int DO_LOGW  = DO_STD + B_ * T_ * M_;
constexpr int DO_CORR  = DO_LOGW + B_ * T_ * M_;
constexpr int DO_LAST  = DO_CORR + B_ * T_ * M_;
constexpr int DO_PHI   = DO_LAST + B_ * T_;
} // namespace

// ---------------------------------------------------------------------------
__device__ __forceinline__ float load_agent(const float* p) {
  return __hip_atomic_load(p, __ATOMIC_RELAXED, __HIP_MEMORY_SCOPE_AGENT);
}
__device__ __forceinline__ void store_agent(float* p, float v) {
  __hip_atomic_store(p, v, __ATOMIC_RELAXED, __HIP_MEMORY_SCOPE_AGENT);
}
__device__ __forceinline__ void store_agent_u32(unsigned* p, unsigned v) {
  __hip_atomic_store(p, v, __ATOMIC_RELAXED, __HIP_MEMORY_SCOPE_AGENT);
}
__device__ __forceinline__ unsigned load_agent_u32(const unsigned* p) {
  return __hip_atomic_load(p, __ATOMIC_RELAXED, __HIP_MEMORY_SCOPE_AGENT);
}
__device__ __forceinline__ unsigned long long load_agent_u64(const unsigned long long* p) {
  return __hip_atomic_load(p, __ATOMIC_RELAXED, __HIP_MEMORY_SCOPE_AGENT);
}
__device__ __forceinline__ ushort_t f2bf(float f) {
  union { float f; unsigned u; } x{f};
  unsigned r = x.u + 0x7FFFu + ((x.u >> 16) & 1u);
  return (ushort_t)(r >> 16);
}
__device__ __forceinline__ void split2(float f, ushort_t& h, ushort_t& l) {
  h = f2bf(f);
  union { unsigned u; float f; } c;
  c.u = ((unsigned)h) << 16;
  l = f2bf(f - c.f);
}
__device__ __forceinline__ float bfpair(ushort_t h, ushort_t l) {
  union { unsigned u; float f; } a, b;
  a.u = ((unsigned)h) << 16; b.u = ((unsigned)l) << 16;
  return a.f + b.f;
}
__device__ __forceinline__ float sigmoidf_(float x) {
  return 1.f / (1.f + __expf(-x));
}

// wave-parallel poll: lane i watches flags[i] (i<nf) until >= target.
// Escalating backoff; s_sleep operand must be a constant -> two call sites.
__device__ __forceinline__ void wave_poll(const unsigned* flags, int nf, int target) {
  if (target <= 0) return;
  const int lane = threadIdx.x & 63;
  const unsigned* p = flags + (lane < nf ? lane : 0);
  int spins = 0;
  for (;;) {
    int v = (int)load_agent_u32(p);
    if (__all(lane >= nf || v >= target)) break;
    if (++spins > 3) __builtin_amdgcn_s_sleep(8);
    else             __builtin_amdgcn_s_sleep(1);
  }
}

// ---------------------------------------------------------------------------
// Staging split into issue (global loads into regs) and write (unpack -> LDS)
// so all rings' loads can be in flight together (one exposed LLC latency).
__device__ __forceinline__ void stage_issue(const unsigned* __restrict__ src,
                                            unsigned long long* v) {
  const int tid = threadIdx.x;
#pragma unroll
  for (int i = 0; i < 12; ++i)
    v[i] = load_agent_u64((const unsigned long long*)(src + (tid + i * 256) * 2));
  if (tid < 128)
    v[12] = load_agent_u64((const unsigned long long*)(src + (3072 + tid) * 2));
}
__device__ __forceinline__ void stage_write(const unsigned long long* v,
                                            ushort_t* __restrict__ BhB,
                                            ushort_t* __restrict__ BlB, int koff) {
  const int tid = threadIdx.x;
#pragma unroll
  for (int i = 0; i < 12; ++i) {
    int e = (tid + i * 256) * 2;
    int b = e / 400, k = e - b * 400;
    unsigned p0 = (unsigned)v[i], p1 = (unsigned)(v[i] >> 32);
    *(unsigned*)(BhB + b * SBL + koff + k) = (p0 >> 16) | (p1 & 0xFFFF0000u);
    *(unsigned*)(BlB + b * SBL + koff + k) = (p0 & 0xFFFFu) | (p1 << 16);
  }
  if (tid < 128) {
    int e = (3072 + tid) * 2;
    int b = e / 400, k = e - b * 400;
    unsigned p0 = (unsigned)v[12], p1 = (unsigned)(v[12] >> 32);
    *(unsigned*)(BhB + b * SBL + koff + k) = (p0 >> 16) | (p1 & 0xFFFF0000u);
    *(unsigned*)(BlB + b * SBL + koff + k) = (p0 & 0xFFFFu) | (p1 << 16);
  }
}

// ---------------------------------------------------------------------------
__global__ __launch_bounds__(256)
void zero_ws(float* __restrict__ p) {
  size_t i = (size_t)blockIdx.x * 256 + threadIdx.x;
  if (i < ZERO_TOT) p[i] = 0.f;
}

__global__ void zero_feat_pads(ushort_t* __restrict__ fh, ushort_t* __restrict__ fl) {
  int idx = blockIdx.x * 256 + threadIdx.x;
  if (idx >= N_ * 48) return;
  int n = idx / 48, r = idx % 48;
  size_t o = (size_t)n * FEAT_LD + (r / 16) * SEG + 400 + (r % 16);
  fh[o] = 0; fl[o] = 0;
}

__global__ void split_wh_kernel(const float* __restrict__ Wh,
                                ushort_t* __restrict__ hi, ushort_t* __restrict__ lo) {
  int idx = blockIdx.x * 256 + threadIdx.x;
  if (idx >= 128 * FEAT_LD) return;
  int m = idx / FEAT_LD, k = idx % FEAT_LD;
  int seg = k / SEG, off = k % SEG;
  float v = (m < 121 && off < 400) ? Wh[(size_t)m * 1200 + seg * 400 + off] : 0.f;
  ushort_t h, l; split2(v, h, l);
  hi[idx] = h; lo[idx] = l;
}

__global__ __launch_bounds__(256)
void gemm_split_kernel(const ushort_t* __restrict__ Ahi, const ushort_t* __restrict__ Alo,
                       const ushort_t* __restrict__ Bhi, const ushort_t* __restrict__ Blo,
                       const float* __restrict__ bias, float* __restrict__ C,
                       int mtiles, int ntiles, int ktiles, int strideA, int strideB,
                       int Mvalid, int ldc) {
  int wave = blockIdx.x * 4 + (threadIdx.x >> 6);
  if (wave >= mtiles * ntiles) return;
  int mt = wave / ntiles, nt = wave % ntiles;
  int lane = threadIdx.x & 63, l15 = lane & 15, quad = lane >> 4;
  size_t aoff = (size_t)(mt * 16 + l15) * strideA + quad * 8;
  size_t boff = (size_t)(nt * 16 + l15) * strideB + quad * 8;
  f32x4 a0 = {0.f, 0.f, 0.f, 0.f}, a1 = a0, a2 = a0;
  for (int kt = 0; kt < ktiles; ++kt) {
    bf16x8 ah = *(const bf16x8*)(Ahi + aoff + kt * 32);
    bf16x8 al = *(const bf16x8*)(Alo + aoff + kt * 32);
    bf16x8 bh = *(const bf16x8*)(Bhi + boff + kt * 32);
    bf16x8 bl = *(const bf16x8*)(Blo + boff + kt * 32);
    a0 = __builtin_amdgcn_mfma_f32_16x16x32_bf16(ah, bh, a0, 0, 0, 0);
    a1 = __builtin_amdgcn_mfma_f32_16x16x32_bf16(ah, bl, a1, 0, 0, 0);
    a2 = __builtin_amdgcn_mfma_f32_16x16x32_bf16(al, bh, a2, 0, 0, 0);
  }
  int n = nt * 16 + l15;
#pragma unroll
  for (int r = 0; r < 4; ++r) {
    int m = mt * 16 + quad * 4 + r;
    if (m < Mvalid) C[(size_t)n * ldc + m] = a0[r] + a1[r] + a2[r] + bias[m];
  }
}

// ---------------------------------------------------------------------------
// fused pipelined scan body (templated per layer)
template <int L>
__device__ __forceinline__ void scan_body(
    int slice, int bhalf,
    const float* __restrict__ x, const int* __restrict__ c,
    const float* __restrict__ Wih, const float* __restrict__ Whh,
    const float* __restrict__ bih, const float* __restrict__ bhh,
    const float* __restrict__ Ww, const float* __restrict__ bw,
    unsigned* __restrict__ ringS, const unsigned* __restrict__ ringP,
    const float* __restrict__ wring_c, float* __restrict__ wring_w,
    ushort_t* __restrict__ fh, ushort_t* __restrict__ fl,
    float* __restrict__ out_phi, unsigned* __restrict__ bar,
    ushort_t* Bh, ushort_t* Bl, float (*su)[65], float (*sp)[33],
    float (*skap)[10], unsigned char (*sc)[64], float (*sw)[60]) {
  constexpr int KT = (L == 0) ? 15 : 27;
  constexpr int CONST_K = (L == 0) ? 463 : 863;
  constexpr int XOFF = (L == 0) ? 460 : 860;
  constexpr int WOFF = (L == 0) ? 400 : 800;
  constexpr int IW = (L == 0) ? 63 : 463;
  const int tid = threadIdx.x;
  const int waveid = tid >> 6, lane = tid & 63;
  const int l15 = lane & 15, quad = lane >> 4;
  const int rt = waveid;                 // rowtile 0..3
  const int m = l15;
  const int uu = m & 3, gate = m >> 2;   // 0=r 1=z 2=hn 3=inn
  const int J = slice * 16 + rt * 4 + uu;
  const int B0 = bhalf * 16;             // first global sample of this block

  // flag plumbing: own / parent / child flag arrays
  unsigned* fOwn    = bar + BAR_FLAGS + 64 * (L * 2 + bhalf);
  unsigned* fParent = (L >= 1) ? bar + BAR_FLAGS + 64 * ((L - 1) * 2 + bhalf) : nullptr;
  unsigned* fChild  = (L <= 1) ? bar + BAR_FLAGS + 64 * ((L + 1) * 2 + bhalf) : nullptr;

  // ---- main A-fragments (split bf16), in registers for all 512 steps ----
  bf16x8 afh[KT], afl[KT];
#pragma unroll
  for (int kt = 0; kt < KT; ++kt) {
    union { bf16x8 v; ushort_t s[8]; } uh, ul;
#pragma unroll
    for (int j = 0; j < 8; ++j) {
      int k = kt * 32 + quad * 8 + j;
      float v = 0.f;
      if (k < 400) {
        if (gate == 0)      v = Whh[(size_t)J * 400 + k];
        else if (gate == 1) v = Whh[(size_t)(400 + J) * 400 + k];
        else if (gate == 2) v = Whh[(size_t)(800 + J) * 400 + k];
      } else if (k < CONST_K) {
        int col;
        if (L == 0) col = (k < 460) ? 3 + (k - 400) : (k - 460);
        else        col = (k < 800) ? 3 + (k - 400)
                        : (k < 860) ? 403 + (k - 800) : (k - 860);
        if (gate == 0)      v = Wih[(size_t)J * IW + col];
        else if (gate == 1) v = Wih[(size_t)(400 + J) * IW + col];
        else if (gate == 3) v = Wih[(size_t)(800 + J) * IW + col];
      } else if (k == CONST_K) {
        if (gate == 0)      v = bih[J] + bhh[J];
        else if (gate == 1) v = bih[400 + J] + bhh[400 + J];
        else if (gate == 2) v = bhh[800 + J];
        else                v = bih[800 + J];
      }
      ushort_t h, l; split2(v, h, l);
      uh.s[j] = h; ul.s[j] = l;
    }
    afh[kt] = uh.v; afl[kt] = ul.v;
  }

  // ---- attention p-fragments (Ww rows, split), L0/L1: waves 0/1 own 16 rows
  bf16x8 apfh[14], apfl[14];
  if constexpr (L <= 1) {
    const int prow = (waveid < 2) ? (waveid * 16 + l15) : 32;
#pragma unroll
    for (int pk = 0; pk < 14; ++pk) {
      int kt = (pk < 13) ? ((L == 0) ? pk : 12 + pk) : ((L == 0) ? 14 : 26);
      union { bf16x8 v; ushort_t s[8]; } uh, ul;
#pragma unroll
      for (int j = 0; j < 8; ++j) {
        int k = kt * 32 + quad * 8 + j;
        int col = k - ((L == 0) ? 0 : 400);
        float v = 0.f;
        if (prow < 30) {
          if (col >= 0 && col < 400) v = Ww[prow * 400 + col];
          else if (k == CONST_K)     v = bw[prow];
        }
        ushort_t h, l; split2(v, h, l);
        uh.s[j] = h; ul.s[j] = l;
      }
      apfh[pk] = uh.v; apfl[pk] = ul.v;
    }
  }

  // ---- one-time LDS init ----
  for (int i = tid; i < 16 * SBL; i += 256) { Bh[i] = 0; Bl[i] = 0; }
  for (int i = tid; i < 160; i += 256) skap[i / 10][i % 10] = 0.f;
  if constexpr (L <= 1) {
    for (int i = tid; i < 16 * 64; i += 256)
      sc[i >> 6][i & 63] = (unsigned char)c[(B0 + (i >> 6)) * U_ + (i & 63)];
  }
  __syncthreads();
  if (tid < 16) Bh[tid * SBL + CONST_K] = 0x3F80;  // bf16(1.0); lo stays 0
  __syncthreads();

  // ---- time loop: dataflow sync via wave-parallel flag polls ----
  for (int t = 0; t < T_; ++t) {
    if (waveid == 0)      wave_poll(fOwn, 25, t);             // peers done t-1
    else if (waveid == 1) { if (L >= 1) wave_poll(fParent, 25, t + 1); }
    else if (waveid == 2) { if (L <= 1) wave_poll(fChild, 25, t - 3); }
    __syncthreads();

    // -- staging ISSUE: all rings' loads in flight together --
    unsigned long long vS[13], vP[13];
    float wv[4] = {0.f, 0.f, 0.f, 0.f};
    float xv = 0.f;
    stage_issue(ringS + (size_t)((t + 3) & 3) * 12800 + B0 * 400, vS);
    if constexpr (L >= 1)
      stage_issue(ringP + (size_t)(t & 3) * 12800 + B0 * 400, vP);
    if constexpr (L == 2) {
      const float* srcw = wring_c + (size_t)(t & 3) * 1920 + B0 * 60;
#pragma unroll
      for (int i = 0; i < 3; ++i) wv[i] = load_agent(srcw + tid + i * 256);
      if (tid < 192) wv[3] = load_agent(srcw + 768 + tid);
    }
    if (tid < 48) xv = x[((size_t)(B0 + tid / 3) * T_ + t) * 3 + (tid % 3)];

    // -- staging WRITE (consume in issue order) --
    stage_write(vS, Bh, Bl, 0);
    if constexpr (L >= 1) stage_write(vP, Bh, Bl, 400);
    if constexpr (L == 2) {
#pragma unroll
      for (int i = 0; i < 3; ++i) {
        int idx = tid + i * 256;
        int b = idx / 60, v = idx - b * 60;
        ushort_t h, l; split2(wv[i], h, l);
        Bh[b * SBL + WOFF + v] = h; Bl[b * SBL + WOFF + v] = l;
      }
      if (tid < 192) {
        int idx = 768 + tid;
        int b = idx / 60, v = idx - b * 60;
        ushort_t h, l; split2(wv[3], h, l);
        Bh[b * SBL + WOFF + v] = h; Bl[b * SBL + WOFF + v] = l;
      }
    }
    if (tid < 48) {
      int b = tid / 3, xc = tid - b * 3;
      ushort_t h, l; split2(xv, h, l);
      Bh[b * SBL + XOFF + xc] = h; Bl[b * SBL + XOFF + xc] = l;
    }
    __syncthreads();

    // -- attention (L0 computes w(t-1) for own input; L1 computes w(t)) --
    if constexpr (L <= 1) {
      const bool dow = (L == 1) || (t > 0);
      if (dow) {
        if (waveid < 2) {  // p-MFMA: rows waveid*16..+15 of 30, cols 16
          f32x4 a0 = {0.f, 0.f, 0.f, 0.f}, a1 = a0, a2 = a0;
          const int brow = l15 * SBL + quad * 8;
#pragma unroll
          for (int pk = 0; pk < 14; ++pk) {
            int kt = (pk < 13) ? ((L == 0) ? pk : 12 + pk) : ((L == 0) ? 14 : 26);
            bf16x8 bh8 = *(const bf16x8*)(Bh + brow + kt * 32);
            bf16x8 bl8 = *(const bf16x8*)(Bl + brow + kt * 32);
            a0 = __builtin_amdgcn_mfma_f32_16x16x32_bf16(apfh[pk], bh8, a0, 0, 0, 0);
            a1 = __builtin_amdgcn_mfma_f32_16x16x32_bf16(apfh[pk], bl8, a1, 0, 0, 0);
            a2 = __builtin_amdgcn_mfma_f32_16x16x32_bf16(apfl[pk], bh8, a2, 0, 0, 0);
          }
#pragma unroll
          for (int r = 0; r < 4; ++r)
            sp[l15][waveid * 16 + quad * 4 + r] = a0[r] + a1[r] + a2[r];
        }
        __syncthreads();
        // ---- wave-local phases: wave owns samples b0..b0+3 ----
        {
          const int b0 = waveid * 4;
          for (int i = lane; i < 120; i += 64) {           // exp(p)
            int b = b0 + i / 30, mm = i % 30;
            sp[b][mm] = __expf(sp[b][mm]);
          }
          if (lane < 40) {                                 // kappa += dk
            int b = b0 + lane / 10, k2 = lane % 10;
            skap[b][k2] += sp[b][20 + k2];
          }
          for (int i = lane; i < 240; i += 64)             // zero w accum
            sw[b0 + i / 60][i % 60] = 0.f;
          for (int i = lane; i < 260; i += 64) {           // phi
            int b = b0 + i / 65, u = i % 65;
            float s = 0.f;
#pragma unroll
            for (int k2 = 0; k2 < 10; ++k2) {
              float d = skap[b][k2] - (float)u;
              s = fmaf(sp[b][k2], __expf(-sp[b][10 + k2] * d * d), s);
            }
            su[b][u] = s;
          }
          for (int i = lane; i < 256; i += 64) {           // scatter phi -> w
            int b = b0 + (i >> 6), u = i & 63;
            atomicAdd(&sw[b][sc[b][u]], su[b][u]);
          }
          for (int i = lane; i < 240; i += 64) {           // write w into B
            int b = b0 + i / 60, v = i % 60;
            float s = sw[b][v];
            ushort_t h, l2; split2(s, h, l2);
            Bh[b * SBL + WOFF + v] = h; Bl[b * SBL + WOFF + v] = l2;
            if (L == 1 && slice == 0)                      // publish w(t) for L2
              store_agent(wring_w + (size_t)(t & 3) * 1920 + (B0 + b) * 60 + v, s);
          }
          if (L == 1 && t == T_ - 1 && slice == 0) {
            for (int i = lane; i < 260; i += 64) {
              int b = b0 + i / 65, u = i % 65;
              out_phi[(B0 + b) * 65 + u] = su[b][u];
            }
          }
        }
        __syncthreads();
      }
    }

    // -- main MFMA: rows = this wave's rowtile, cols = 16 samples --
    {
      f32x4 a0 = {0.f, 0.f, 0.f, 0.f}, a1 = a0, a2 = a0;
      const int brow = l15 * SBL + quad * 8;
#pragma unroll
      for (int kt = 0; kt < KT; ++kt) {
        bf16x8 bh8 = *(const bf16x8*)(Bh + brow + kt * 32);
        bf16x8 bl8 = *(const bf16x8*)(Bl + brow + kt * 32);
        a0 = __builtin_amdgcn_mfma_f32_16x16x32_bf16(afh[kt], bh8, a0, 0, 0, 0);
        a1 = __builtin_amdgcn_mfma_f32_16x16x32_bf16(afh[kt], bl8, a1, 0, 0, 0);
        a2 = __builtin_amdgcn_mfma_f32_16x16x32_bf16(afl[kt], bh8, a2, 0, 0, 0);
      }
#pragma unroll
      for (int r = 0; r < 4; ++r)
        su[l15][rt * 16 + quad * 4 + r] = a0[r] + a1[r] + a2[r];  // su as sdots
    }
    __syncthreads();

    // -- combine: 256 threads = 16 samples x 16 units (unit fastest) --
    ushort_t hh, hl;
    const int cb = tid >> 4, cu = tid & 15;
    {
      int urt = cu >> 2, u3 = cu & 3;
      float rr = sigmoidf_(su[cb][urt * 16 + 0 * 4 + u3]);
      float zz = sigmoidf_(su[cb][urt * 16 + 1 * 4 + u3]);
      float hn = su[cb][urt * 16 + 2 * 4 + u3];
      float inn = su[cb][urt * 16 + 3 * 4 + u3];
      int Jc = slice * 16 + cu;
      float hold = bfpair(Bh[cb * SBL + Jc], Bl[cb * SBL + Jc]);
      float hv = (1.f - zz) * tanhf(inn + rr * hn) + zz * hold;
      split2(hv, hh, hl);
      store_agent_u32(ringS + (size_t)(t & 3) * 12800 + (B0 + cb) * 400 + Jc,
                      ((unsigned)hh << 16) | (unsigned)hl);
    }

    // -- drain ring/wring stores, publish own flag (t+1) --
    __builtin_amdgcn_s_waitcnt(0);
    __syncthreads();
    if (tid == 0) store_agent_u32(fOwn + slice, (unsigned)(t + 1));

    // -- feature stores AFTER flag: consumers (gemm) are kernel-boundary
    //    ordered; their latency overlaps the next step's poll+staging --
    {
      int n = (B0 + cb) * T_ + t;
      size_t fo = (size_t)n * FEAT_LD + L * SEG + (slice * 16 + cu);
      fh[fo] = hh; fl[fo] = hl;
    }
  }
}

__global__ __launch_bounds__(256, 1)
void fused_scan(const float* __restrict__ x, const int* __restrict__ c,
                const float* Wih0, const float* Whh0, const float* bih0, const float* bhh0,
                const float* Wih1, const float* Whh1, const float* bih1, const float* bhh1,
                const float* Wih2, const float* Whh2, const float* bih2, const float* bhh2,
                const float* __restrict__ Ww, const float* __restrict__ bw,
                unsigned* ring0, unsigned* ring1, unsigned* ring2, float* wring,
                ushort_t* __restrict__ fh, ushort_t* __restrict__ fl,
                float* __restrict__ out_phi, unsigned* __restrict__ bar) {
  __shared__ ushort_t Bh[16 * SBL];
  __shared__ ushort_t Bl[16 * SBL];
  __shared__ float su[16][65];     // sdots (64 rows) UNION sphi (65)
  __shared__ float sp[16][33];     // attention p (exp'ed); rows 30,31 unused
  __shared__ float skap[16][10];
  __shared__ unsigned char sc[16][64];
  __shared__ float sw[16][60];     // w scatter accumulator

  const int bx = blockIdx.x;
  const int grpL = bx / 50, r = bx % 50;
  const int slice = r >> 1, bhalf = r & 1;

  if (grpL == 0)
    scan_body<0>(slice, bhalf, x, c, Wih0, Whh0, bih0, bhh0, Ww, bw,
                 ring0, nullptr, nullptr, nullptr, fh, fl, out_phi, bar,
                 Bh, Bl, su, sp, skap, sc, sw);
  else if (grpL == 1)
    scan_body<1>(slice, bhalf, x, c, Wih1, Whh1, bih1, bhh1, Ww, bw,
                 ring1, ring0, nullptr, wring, fh, fl, out_phi, bar,
                 Bh, Bl, su, sp, skap, sc, sw);
  else
    scan_body<2>(slice, bhalf, x, c, Wih2, Whh2, bih2, bhh2, Ww, bw,
                 ring2, ring1, wring, nullptr, fh, fl, out_phi, bar,
                 Bh, Bl, su, sp, skap, sc, sw);
}

// ---------------------------------------------------------------------------
__global__ __launch_bounds__(256)
void post_kernel(const float* __restrict__ p, float* __restrict__ dout) {
  int n = blockIdx.x * 256 + threadIdx.x;
  if (n >= N_) return;
  const float* r = p + (size_t)n * 128;
  dout[DO_LAST + n] = r[0];
  float mx = -1e30f;
  for (int m = 0; m < M_; ++m) mx = fmaxf(mx, r[1 + m]);
  float s = 0.f;
  for (int m = 0; m < M_; ++m) s += __expf(r[1 + m] - mx);
  float lse = mx + logf(s);
  for (int m = 0; m < M_; ++m) dout[DO_LOGW + (size_t)n * M_ + m] = r[1 + m] - lse;
  for (int i = 0; i < 2 * M_; ++i) dout[DO_MEANS + (size_t)n * 2 * M_ + i] = r[21 + i];
  for (int m = 0; m < M_; ++m) dout[DO_STD + (size_t)n * M_ + m] = __expf(r[61 + m]);
  for (int m = 0; m < M_; ++m) dout[DO_CORR + (size_t)n * M_ + m] = tanhf(r[81 + m]);
}

// ---------------------------------------------------------------------------
extern "C" void kernel_launch(void* const* d_in, const int* in_sizes, int n_in,
                              void* d_out, int out_size, void* d_ws, size_t ws_size,
                              hipStream_t stream) {
  const float* x    = (const float*)d_in[0];
  const int*   c    = (const int*)d_in[1];
  const float* Wih0 = (const float*)d_in[2];
  const float* Whh0 = (const float*)d_in[3];
  const float* bih0 = (const float*)d_in[4];
  const float* bhh0 = (const float*)d_in[5];
  const float* Wih1 = (const float*)d_in[6];
  const float* Whh1 = (const float*)d_in[7];
  const float* bih1 = (const float*)d_in[8];
  const float* bhh1 = (const float*)d_in[9];
  const float* Wih2 = (const float*)d_in[10];
  const float* Whh2 = (const float*)d_in[11];
  const float* bih2 = (const float*)d_in[12];
  const float* bhh2 = (const float*)d_in[13];
  const float* Ww   = (const float*)d_in[14];
  const float* bw   = (const float*)d_in[15];
  const float* Wh   = (const float*)d_in[16];
  const float* bh   = (const float*)d_in[17];
  (void)in_sizes; (void)n_in; (void)out_size; (void)ws_size;

  float* ws = (float*)d_ws;
  unsigned* ring0 = (unsigned*)(ws + OFF_R0);
  unsigned* ring1 = (unsigned*)(ws + OFF_R1);
  unsigned* ring2 = (unsigned*)(ws + OFF_R2);
  float*    wring = ws + OFF_WRING;
  unsigned* bar   = (unsigned*)(ws + OFF_BAR);
  ushort_t* fh    = (ushort_t*)(ws + OFF_FEATH);
  ushort_t* fl    = (ushort_t*)(ws + OFF_FEATL);
  ushort_t* whh_  = (ushort_t*)(ws + OFF_WHH);
  ushort_t* whl_  = (ushort_t*)(ws + OFF_WHL);
  float*    pbuf  = ws + OFF_P;
  float*    dout  = (float*)d_out;

  const dim3 blk(256);

  zero_ws<<<dim3((int)((ZERO_TOT + 255) / 256)), blk, 0, stream>>>(ws);
  zero_feat_pads<<<dim3((N_ * 48) / 256), blk, 0, stream>>>(fh, fl);
  split_wh_kernel<<<dim3((128 * FEAT_LD) / 256), blk, 0, stream>>>(Wh, whh_, whl_);

  fused_scan<<<dim3(NBLK), blk, 0, stream>>>(
      x, c, Wih0, Whh0, bih0, bhh0, Wih1, Whh1, bih1, bhh1,
      Wih2, Whh2, bih2, bhh2, Ww, bw,
      ring0, ring1, ring2, wring, fh, fl, dout + DO_PHI, bar);

  gemm_split_kernel<<<dim3(8 * (N_ / 16) / 4), blk, 0, stream>>>(
      whh_, whl_, fh, fl, bh, pbuf, 8, N_ / 16, FEAT_LD / 32,
      FEAT_LD, FEAT_LD, 121, 128);
  post_kernel<<<dim3(N_ / 256), blk, 0, stream>>>(pbuf, dout);
}